// Round 15
// baseline (353.869 us; speedup 1.0000x reference)
//
#include <hip/hip_runtime.h>

// LatentVolatilityModel: GRU (H=16), scalar input, T=2^20.
// Round 15: r14 PASSED (314us rocprof) but at 2 waves/SIMD the LDS h-transport
// is latency-exposed: wall 736 cy/step vs readlane spine 387 cy (r7), busy 54%.
// The ds_write->lgkmcnt->ds_read round-trip sits ON the h recurrence.
// Single change vs r14: revert transport to r9's PROVEN readlane body
// (bit-identical output in r9), keep r14's PROVEN segmentation L=512/W=512.
// Expected: back to issue-bound (2x~225cy demand > ~390cy chain).
//
// Lane map (gate rows of [r;z;n] = rows 0..47):
//   lanes 0-15: r   lanes 16-31: z   lanes 32-47: n AND host of h
//   lanes 48-63: clamped finite garbage (never consumed)
// Weights prescaled into exp2 domain: r/z rows * (-log2 e); n rows * (+2 log2 e).
// r->n move: v_permlane32_swap_b32 (runtime-probed semantics, shfl fallback).
// y reduced in-wave (xor-shuffle over the 16-lane h group) on output steps.

#define LOG2E 1.4426950408889634f

__device__ __forceinline__ float rl(float v, int lane) {
    return __int_as_float(__builtin_amdgcn_readlane(__float_as_int(v), lane));
}
__device__ __forceinline__ float fast_rcp(float x) {
    return __builtin_amdgcn_rcpf(x);
}
__device__ __forceinline__ float fast_exp2(float x) {
    return __builtin_amdgcn_exp2f(x);
}

#if __has_builtin(__builtin_amdgcn_permlane32_swap)
#define HAVE_PL32 1
#else
#define HAVE_PL32 0
#endif

__device__ __forceinline__ int probe_rsel() {
    int rsel = 2;
#if HAVE_PL32
    const int lid = (int)threadIdx.x;
    auto p = __builtin_amdgcn_permlane32_swap(lid, lid, false, false);
    const int a32 = __builtin_amdgcn_readlane(p[0], 32);
    const int a47 = __builtin_amdgcn_readlane(p[0], 47);
    const int b32 = __builtin_amdgcn_readlane(p[1], 32);
    const int b47 = __builtin_amdgcn_readlane(p[1], 47);
    if      (a32 == 0 && a47 == 15) rsel = 0;
    else if (b32 == 0 && b47 == 15) rsel = 1;
#endif
    return rsel;
}

// GRU scan over `total` steps on xseg; for steps kk >= warm, reduce y in-wave
// and store y_dst[kk - warm]. RSEL: 0/1 -> permlane32_swap component; 2 -> shfl.
// Transport: h broadcast via 16x v_readlane (r9-proven, low-latency spine).
template <int RSEL>
__device__ __forceinline__ void gru_scan_y(
    const float* __restrict__ xseg,
    int total, int warm, int xclamp,
    const float* __restrict__ W_ih,
    const float* __restrict__ W_hh,
    const float* __restrict__ b_ih,
    const float* __restrict__ b_hh,
    const float* __restrict__ W_out,
    const float* __restrict__ b_out,
    float* __restrict__ y_dst)
{
    const int lane  = threadIdx.x;
    const int row   = lane < 48 ? lane : 47;
    const bool is_n = (lane >= 32);

    const float gscale = is_n ? (2.0f * LOG2E) : (-LOG2E);

    const float w_i   = W_ih[row] * gscale;
    const float bi    = b_ih[row] * gscale;
    const float bh    = b_hh[row] * gscale;
    const float cinit = is_n ? bh : (bi + bh);   // n-lane chain init: bh ONLY
    const float wie   = is_n ? 0.0f : w_i;       // n lanes keep gi out of chain
    float wh[16];
#pragma unroll
    for (int j = 0; j < 16; ++j) wh[j] = W_hh[row * 16 + j] * gscale;

    const int zsrc = (lane & 15) + 16;           // z_j source lane

    const float wout    = (is_n && lane < 48) ? W_out[lane - 32] : 0.0f;
    const float b_out_s = b_out[0];

    float h_v = 0.0f;                            // lanes 32-47 host h

    float xn = xseg[lane <= xclamp ? lane : xclamp];
    const int nch = (total + 63) >> 6;

    for (int c = 0; c < nch; ++c) {
        const float xc = xn;
        {   // prefetch next 64-step chunk (clamped)
            int i2 = ((c + 1) << 6) + lane;
            if (i2 > xclamp) i2 = xclamp;
            xn = xseg[i2];
        }
        const int base = c << 6;
        int m = total - base;
        if (m > 64) m = 64;

#pragma unroll 2
        for (int k = 0; k < m; ++k) {
            const float xt   = rl(xc, k);            // uniform scalar x_t
            const float init = fmaf(wie, xt, cinit); // r/z: gi+bi+bh ; n: bh
            const float gin  = fmaf(w_i, xt, bi);    // n-lane gi (scaled)

            // ---- broadcast h (lanes 32-47) to SGPRs ----
            const float h0  = rl(h_v, 32), h1  = rl(h_v, 33);
            const float h2  = rl(h_v, 34), h3  = rl(h_v, 35);
            const float h4  = rl(h_v, 36), h5  = rl(h_v, 37);
            const float h6  = rl(h_v, 38), h7  = rl(h_v, 39);
            const float h8  = rl(h_v, 40), h9  = rl(h_v, 41);
            const float h10 = rl(h_v, 42), h11 = rl(h_v, 43);
            const float h12 = rl(h_v, 44), h13 = rl(h_v, 45);
            const float h14 = rl(h_v, 46), h15 = rl(h_v, 47);

            // ---- matvec: scaled W_hh[row].h + init, 4 ILP chains ----
            float s0 = fmaf(wh[0], h0, init);
            float s1 = wh[1] * h1;
            float s2 = wh[2] * h2;
            float s3 = wh[3] * h3;
            s0 = fmaf(wh[4],  h4,  s0);
            s1 = fmaf(wh[5],  h5,  s1);
            s2 = fmaf(wh[6],  h6,  s2);
            s3 = fmaf(wh[7],  h7,  s3);
            s0 = fmaf(wh[8],  h8,  s0);
            s1 = fmaf(wh[9],  h9,  s1);
            s2 = fmaf(wh[10], h10, s2);
            s3 = fmaf(wh[11], h11, s3);
            s0 = fmaf(wh[12], h12, s0);
            s1 = fmaf(wh[13], h13, s1);
            s2 = fmaf(wh[14], h14, s2);
            s3 = fmaf(wh[15], h15, s3);
            const float acc = (s0 + s1) + (s2 + s3);

            // ---- sigmoid (valid on r/z; finite on n) ----
            const float sg = fast_rcp(1.0f + fast_exp2(acc));

            // ---- r -> n lanes (on-spine) ----
            float rr;
#if HAVE_PL32
            if constexpr (RSEL != 2) {
                auto q = __builtin_amdgcn_permlane32_swap(
                    __float_as_int(sg), __float_as_int(sg), false, false);
                rr = __int_as_float(q[RSEL]);
            } else
#endif
            {
                rr = __shfl(sg, lane & 31);
            }

            // ---- z -> n lanes (issued now, consumed at tail) ----
            const float zz = __shfl(sg, zsrc);

            // ---- n gate spine ----
            const float a2 = fmaf(rr, acc, gin);     // 2log2e*(gi_n + r*gh_n)
            const float e  = fast_exp2(a2);
            const float u  = fast_rcp(1.0f + e);
            const float nv = fmaf(-2.0f, u, 1.0f);   // tanh

            // ---- combine (lanes 32-47) ----
            const float hnew = fmaf(zz, h_v - nv, nv);   // (1-z)*n + z*h
            h_v = hnew;

            // ---- y output for post-warmup steps ----
            const int kk = base + k;
            if (kk >= warm) {                        // wave-uniform branch
                float p = wout * hnew;               // nonzero only lanes 32-47
                p += __shfl_xor(p, 1);
                p += __shfl_xor(p, 2);
                p += __shfl_xor(p, 4);
                p += __shfl_xor(p, 8);
                if (lane == 32) y_dst[kk - warm] = p + b_out_s;
            }
        }
    }
}

// Segment-parallel washout: segment seg owns y[seg*L .. seg*L+Lc), warmed up
// from h=0 over w0 = min(W, segstart) prior steps (early segments: exact
// full-history warmup; t0 never negative).
__global__ __launch_bounds__(64)
void gru_washout(const float* __restrict__ x,
                 const float* __restrict__ W_ih,
                 const float* __restrict__ W_hh,
                 const float* __restrict__ b_ih,
                 const float* __restrict__ b_hh,
                 const float* __restrict__ W_out,
                 const float* __restrict__ b_out,
                 float* __restrict__ y,
                 int nsteps, int L, int W)
{
    const int seg      = blockIdx.x;
    const int segstart = seg * L;
    if (segstart >= nsteps) return;
    int Lc = nsteps - segstart;
    if (Lc > L) Lc = L;
    const int w0     = segstart < W ? segstart : W;   // clamp: t0 >= 0 always
    const int t0     = segstart - w0;
    const int xclamp = nsteps - t0;      // x valid up to global index nsteps

    const int rsel = probe_rsel();
    if (rsel == 0)
        gru_scan_y<0>(x + t0, w0 + Lc, w0, xclamp, W_ih, W_hh, b_ih, b_hh, W_out, b_out, y + segstart);
    else if (rsel == 1)
        gru_scan_y<1>(x + t0, w0 + Lc, w0, xclamp, W_ih, W_hh, b_ih, b_hh, W_out, b_out, y + segstart);
    else
        gru_scan_y<2>(x + t0, w0 + Lc, w0, xclamp, W_ih, W_hh, b_ih, b_hh, W_out, b_out, y + segstart);
}

extern "C" void kernel_launch(void* const* d_in, const int* in_sizes, int n_in,
                              void* d_out, int out_size, void* d_ws, size_t ws_size,
                              hipStream_t stream) {
    const float* x     = (const float*)d_in[0];
    const float* W_ih  = (const float*)d_in[1];
    const float* W_hh  = (const float*)d_in[2];
    const float* b_ih  = (const float*)d_in[3];
    const float* b_hh  = (const float*)d_in[4];
    const float* W_out = (const float*)d_in[5];
    const float* b_out = (const float*)d_in[6];
    float* y = (float*)d_out;
    const int nsteps = out_size;                      // T-1 = 1048575

    const int L = 512;                                // output steps per segment
    const int W = 512;                                // warmup (r14 PROVEN:
                                                      // absmax bit-identical)
    const int P = (nsteps + L - 1) / L;               // 2048 segments

    gru_washout<<<P, 64, 0, stream>>>(x, W_ih, W_hh, b_ih, b_hh, W_out, b_out,
                                      y, nsteps, L, W);
}